// Round 14
// baseline (1253.242 us; speedup 1.0000x reference)
//
#include <hip/hip_runtime.h>
#include <hip/hip_bf16.h>

// Problem constants (from reference)
#define LL 2000
#define MM 3
#define FF 512
#define NN (MM * LL)          // 6000 nodes
#define CAP 128               // bucket capacity; deg ~ N(66.7, 8.2) -> P(any>128) ~ 1e-9
#define GXM 94                // ceil(6000/64)
#define GRID 1024             // 4 blocks/CU x 256 CUs -> all co-resident

typedef __attribute__((ext_vector_type(8))) short bf16x8;
typedef __attribute__((ext_vector_type(4))) float f32x4;

__device__ __forceinline__ unsigned short f2bf(float x) {
    __hip_bfloat16 b = __float2bfloat16(x);
    return *(unsigned short*)&b;
}

// async global->LDS, 16B per lane. lds dest is wave-uniform base + lane*16.
__device__ __forceinline__ void gload16(const void* gsrc, void* ldst) {
    __builtin_amdgcn_global_load_lds((const __attribute__((address_space(1))) unsigned int*)gsrc,
                                     (__attribute__((address_space(3))) unsigned int*)ldst,
                                     16, 0, 0);
}

// ---------------------------------------------------------------------------
// Manual grid barrier: all GRID blocks are co-resident (guaranteed by
// __launch_bounds__(256,4)). Device-scope atomics are XCD-coherent; the
// __threadfence pair gives release/acquire for normal loads/stores.
// ---------------------------------------------------------------------------
__device__ __forceinline__ void gridbar(int* bar, int target) {
    __syncthreads();
    if (threadIdx.x == 0) {
        __threadfence();                 // release: drain this block's writes
        atomicAdd(bar, 1);
        while (atomicAdd(bar, 0) < target) __builtin_amdgcn_s_sleep(8);
    }
    __syncthreads();
    __threadfence();                     // acquire: invalidate stale cache
}

// ---------------------------------------------------------------------------
// 64x64 MFMA GEMM tile (BK=64, 4 waves 2x2 of 32x32, XOR-swizzled LDS).
// MODE 0: Hout[m*FF+n] = bf16(acc)      MODE 1: out[m*FF+n] += leaky(acc+bias)
// ---------------------------------------------------------------------------
template <int MODE>
__device__ void gemm_tile(short* As, short* Bs,
                          const unsigned short* __restrict__ A,
                          const unsigned short* __restrict__ Bt,
                          const float* __restrict__ fbias,
                          unsigned short* __restrict__ Hout,
                          float* __restrict__ out,
                          int M, int m0, int n0, int tid) {
    int wave = tid >> 6;
    int lane = tid & 63;
    int lane16 = lane & 15;
    int quad = lane >> 4;
    int wm = (wave >> 1) * 32;
    int wn = (wave & 1) * 32;

    f32x4 acc[2][2] = {};

    for (int k0 = 0; k0 < FF; k0 += 64) {
#pragma unroll
        for (int s = 0; s < 2; s++) {
            int c = wave * 128 + s * 64 + lane;
            int row = c >> 3;
            int kc = (c & 7) ^ (row & 7);
            int ar = m0 + row; if (ar >= M) ar = M - 1;
            gload16((const short*)A + (size_t)ar * FF + k0 + kc * 8,
                    &As[(wave * 128 + s * 64) * 8]);
            gload16((const short*)Bt + (size_t)(n0 + row) * FF + k0 + kc * 8,
                    &Bs[(wave * 128 + s * 64) * 8]);
        }
        __syncthreads();
#pragma unroll
        for (int kk = 0; kk < 2; kk++) {
            bf16x8 a[2], bb[2];
#pragma unroll
            for (int mt = 0; mt < 2; mt++) {
                int row = wm + mt * 16 + lane16;
                int kc = (kk * 4 + quad) ^ (row & 7);
                a[mt] = *(const bf16x8*)&As[row * 64 + kc * 8];
            }
#pragma unroll
            for (int nt = 0; nt < 2; nt++) {
                int row = wn + nt * 16 + lane16;
                int kc = (kk * 4 + quad) ^ (row & 7);
                bb[nt] = *(const bf16x8*)&Bs[row * 64 + kc * 8];
            }
#pragma unroll
            for (int mt = 0; mt < 2; mt++)
#pragma unroll
                for (int nt = 0; nt < 2; nt++)
                    acc[mt][nt] = __builtin_amdgcn_mfma_f32_16x16x32_bf16(a[mt], bb[nt], acc[mt][nt], 0, 0, 0);
        }
        __syncthreads();
    }

#pragma unroll
    for (int mt = 0; mt < 2; mt++) {
#pragma unroll
        for (int nt = 0; nt < 2; nt++) {
            int n = n0 + wn + nt * 16 + lane16;
            float bv = (MODE == 1) ? fbias[n] : 0.0f;
#pragma unroll
            for (int rr = 0; rr < 4; rr++) {
                int m = m0 + wm + mt * 16 + quad * 4 + rr;
                if (m < M) {
                    float v = acc[mt][nt][rr];
                    if (MODE == 1) {
                        v += bv;
                        v = (v > 0.0f) ? v : 0.01f * v;
                        out[(size_t)m * FF + n] += v;
                    } else {
                        Hout[(size_t)m * FF + n] = f2bf(v);
                    }
                }
            }
        }
    }
}

// ---------------------------------------------------------------------------
// SpMM row unit over packed 4B buckets {bf16(w)<<16 | col}: one wave per row,
// lane covers 8 features; 4 edges prefetched per uint4 load.
// ---------------------------------------------------------------------------
__device__ __forceinline__ void accum8(float* acc, uint4 h, float v) {
    unsigned int d[4] = {h.x, h.y, h.z, h.w};
#pragma unroll
    for (int k = 0; k < 4; k++) {
        float lo = __uint_as_float(d[k] << 16);
        float hi = __uint_as_float(d[k] & 0xFFFF0000u);
        acc[2 * k]     = fmaf(v, lo, acc[2 * k]);
        acc[2 * k + 1] = fmaf(v, hi, acc[2 * k + 1]);
    }
}

__device__ void spmm_unit(const unsigned short* __restrict__ H,
                          const int* __restrict__ counts,
                          const unsigned int* __restrict__ bucket,
                          const float* __restrict__ dinv,
                          const float* __restrict__ bias,
                          unsigned short* __restrict__ featOut,
                          int r, int lane) {
    int s = r * CAP;
    int e = s + min(counts[r], CAP);
    int f0 = lane * 8;
    const unsigned short* Hf = H + f0;
    float acc[8] = {0, 0, 0, 0, 0, 0, 0, 0};

    int i = s;
    uint4 pk;
    bool have = (i + 4 <= e);
    if (have) pk = *(const uint4*)&bucket[i];
    while (have) {
        unsigned int q0 = pk.x, q1 = pk.y, q2 = pk.z, q3 = pk.w;
        uint4 a0 = *(const uint4*)(Hf + (size_t)(q0 & 0xFFFF) * FF);
        uint4 a1 = *(const uint4*)(Hf + (size_t)(q1 & 0xFFFF) * FF);
        uint4 a2 = *(const uint4*)(Hf + (size_t)(q2 & 0xFFFF) * FF);
        uint4 a3 = *(const uint4*)(Hf + (size_t)(q3 & 0xFFFF) * FF);
        float v0 = __uint_as_float(q0 & 0xFFFF0000u) * dinv[q0 & 0xFFFF];
        float v1 = __uint_as_float(q1 & 0xFFFF0000u) * dinv[q1 & 0xFFFF];
        float v2 = __uint_as_float(q2 & 0xFFFF0000u) * dinv[q2 & 0xFFFF];
        float v3 = __uint_as_float(q3 & 0xFFFF0000u) * dinv[q3 & 0xFFFF];
        i += 4;
        have = (i + 4 <= e);
        if (have) pk = *(const uint4*)&bucket[i];
        accum8(acc, a0, v0);
        accum8(acc, a1, v1);
        accum8(acc, a2, v2);
        accum8(acc, a3, v3);
    }
    for (; i < e; i++) {
        unsigned int q = bucket[i];
        uint4 a = *(const uint4*)(Hf + (size_t)(q & 0xFFFF) * FF);
        accum8(acc, a, __uint_as_float(q & 0xFFFF0000u) * dinv[q & 0xFFFF]);
    }

    float dr = dinv[r];
    float4 b0 = *(const float4*)(bias + f0);
    float4 b1 = *(const float4*)(bias + f0 + 4);
    float bb[8] = {b0.x, b0.y, b0.z, b0.w, b1.x, b1.y, b1.z, b1.w};
    unsigned int o[4];
#pragma unroll
    for (int k = 0; k < 4; k++) {
        float v0 = fmaxf(fmaf(acc[2 * k], dr, bb[2 * k]), 0.0f);
        float v1 = fmaxf(fmaf(acc[2 * k + 1], dr, bb[2 * k + 1]), 0.0f);
        o[k] = (unsigned int)f2bf(v0) | ((unsigned int)f2bf(v1) << 16);
    }
    uint4 ov; ov.x = o[0]; ov.y = o[1]; ov.z = o[2]; ov.w = o[3];
    *(uint4*)(featOut + (size_t)r * FF + f0) = ov;
}

// ---------------------------------------------------------------------------
// Fused megakernel, manual grid barriers. GRID=1024 blocks, 4/CU resident.
// Phases:
//  1: concat + wtrans + edge histogram (pir)        [bar -> 1*GRID]
//  2: scatter (atomic-free) || gemm0: H0=feat0@gW0  [bar -> 2*GRID]
//  3: rowsum over buckets -> dinv                   [bar -> 3*GRID]
//  4: spmm1: feat1 = relu(gcn@H0 + gb0)             [bar -> 4*GRID]
//  5: gemm2: out += leaky(feat1@fW0+fb0) & H1       [bar -> 5*GRID]
//  6: spmm2: feat2 = relu(gcn@H1 + gb1)             [bar -> 6*GRID]
//  7: out += leaky(feat2@fW1 + fb1)
// counts + bar zeroed by host memset before launch.
// ---------------------------------------------------------------------------
__global__ __launch_bounds__(256, 4) void fused(
        const float* __restrict__ xa, const float* __restrict__ xv,
        const float* __restrict__ xt, const float* __restrict__ ew,
        const float* __restrict__ gcnW, const float* __restrict__ gcn_b,
        const float* __restrict__ fcW, const float* __restrict__ fc_b,
        const int* __restrict__ esrc, const int* __restrict__ edst, int E,
        int* __restrict__ counts, int* bar, int* __restrict__ pir,
        unsigned int* __restrict__ bucket, float* __restrict__ dinv,
        unsigned short* __restrict__ feat, unsigned short* __restrict__ H,
        unsigned short* __restrict__ Wt, float* __restrict__ out) {
    __shared__ short smem[2 * 64 * 64];   // 16 KB
    short* As = smem;
    short* Bs = smem + 64 * 64;
    const int tid = threadIdx.x;
    const int wave = tid >> 6, lane = tid & 63;
    const int G = GRID;
    const int eblocks = (E + 255) / 256;

    // ---- phase 1: concat + wtrans + histogram ----
    {
        const int U = 3000 + 256 + eblocks;
        for (int u = blockIdx.x; u < U; u += G) {
            if (u < 3000) {
                int idx4 = u * 256 + tid;
                const int per4 = (LL * FF) / 4;
                const float4* src;
                int off;
                if (idx4 < per4)          { src = (const float4*)xa; off = idx4; }
                else if (idx4 < 2 * per4) { src = (const float4*)xv; off = idx4 - per4; }
                else                      { src = (const float4*)xt; off = idx4 - 2 * per4; }
                float4 v = src[off];
                ((float4*)out)[idx4] = v;
                ushort4 p;
                p.x = f2bf(v.x); p.y = f2bf(v.y); p.z = f2bf(v.z); p.w = f2bf(v.w);
                ((ushort4*)feat)[idx4] = p;
            } else if (u < 3256) {
                int idx = u - 3000;
                int mz = idx >> 6;
                int rem = idx & 63;
                int k0 = (rem >> 3) * 64;
                int n0 = (rem & 7) * 64;
                int layer = (mz < 2) ? mz : mz - 2;
                const float* src = (mz < 2) ? (gcnW + (size_t)layer * FF * FF)
                                            : (fcW + (size_t)layer * FF * FF);
                int slot = (mz < 2) ? (mz * 2) : ((mz - 2) * 2 + 1);
                unsigned short* dst = Wt + (size_t)slot * FF * FF;
                unsigned short* tile = (unsigned short*)smem;   // [64][65]
                for (int i = tid; i < 64 * 64; i += 256) {
                    int r = i >> 6, c = i & 63;
                    tile[r * 65 + c] = f2bf(src[(size_t)(k0 + r) * FF + n0 + c]);
                }
                __syncthreads();
                for (int i = tid; i < 64 * 64; i += 256) {
                    int r = i >> 6, c = i & 63;
                    dst[(size_t)(n0 + r) * FF + k0 + c] = tile[c * 65 + r];
                }
                __syncthreads();
            } else {
                int e = (u - 3256) * 256 + tid;
                if (e < E) pir[e] = atomicAdd(&counts[esrc[e]], 1);
            }
        }
    }
    gridbar(bar, 1 * GRID);

    // ---- phase 2: scatter || gemm0 (H0 = feat0 @ gW0) ----
    {
        const int U = eblocks + GXM * 8;
        for (int u = blockIdx.x; u < U; u += G) {
            if (u < eblocks) {
                int e = u * 256 + tid;
                if (e < E) {
                    int r = esrc[e];
                    int slot = pir[e];
                    if (slot < CAP)
                        bucket[(size_t)r * CAP + slot] =
                            ((unsigned int)f2bf(ew[e]) << 16) | (unsigned int)edst[e];
                }
            } else {
                int ug = u - eblocks;
                gemm_tile<0>(As, Bs, feat, Wt, nullptr, H, nullptr,
                             NN, (ug % GXM) * 64, (ug / GXM) * 64, tid);
            }
        }
    }
    gridbar(bar, 2 * GRID);

    // ---- phase 3: rowsum -> dinv ----
    for (int u = blockIdx.x; u < NN / 4; u += G) {
        int r = u * 4 + wave;
        int s = r * CAP;
        int e = s + min(counts[r], CAP);
        float sum = 0.0f;
        for (int i = s + lane; i < e; i += 64)
            sum += __uint_as_float(bucket[i] & 0xFFFF0000u);
#pragma unroll
        for (int off = 32; off > 0; off >>= 1) sum += __shfl_xor(sum, off);
        if (lane == 0) dinv[r] = (sum > 0.0f) ? rsqrtf(sum) : 0.0f;
    }
    gridbar(bar, 3 * GRID);

    // ---- phase 4: spmm1 -> feat1 ----
    for (int u = blockIdx.x; u < NN / 4; u += G)
        spmm_unit(H, counts, bucket, dinv, gcn_b, feat, u * 4 + wave, lane);
    gridbar(bar, 4 * GRID);

    // ---- phase 5: gemm2 (fc0 -> out, gcn1 -> H1), Bt = [fW0^T ; gW1^T] ----
    {
        const unsigned short* Bt = Wt + (size_t)FF * FF;
        for (int u = blockIdx.x; u < GXM * 16; u += G) {
            int m0 = (u % GXM) * 64;
            int n0 = (u / GXM) * 64;
            if (n0 < FF)
                gemm_tile<1>(As, Bs, feat, Bt, fc_b, nullptr, out, NN, m0, n0, tid);
            else
                gemm_tile<0>(As, Bs, feat, Bt, nullptr, H - FF, nullptr, NN, m0, n0, tid);
        }
    }
    gridbar(bar, 5 * GRID);

    // ---- phase 6: spmm2 -> feat2 ----
    for (int u = blockIdx.x; u < NN / 4; u += G)
        spmm_unit(H, counts, bucket, dinv, gcn_b + FF, feat, u * 4 + wave, lane);
    gridbar(bar, 6 * GRID);

    // ---- phase 7: out += leaky(feat2 @ fW1 + fb1) ----
    {
        const unsigned short* Bt = Wt + (size_t)3 * FF * FF;
        for (int u = blockIdx.x; u < GXM * 8; u += G)
            gemm_tile<1>(As, Bs, feat, Bt, fc_b + FF, nullptr, out,
                         NN, (u % GXM) * 64, (u / GXM) * 64, tid);
    }
}

// ---------------------------------------------------------------------------
extern "C" void kernel_launch(void* const* d_in, const int* in_sizes, int n_in,
                              void* d_out, int out_size, void* d_ws, size_t ws_size,
                              hipStream_t stream) {
    const float* xa    = (const float*)d_in[0];
    const float* xv    = (const float*)d_in[1];
    const float* xt    = (const float*)d_in[2];
    const float* ew    = (const float*)d_in[3];
    const float* gcn_W = (const float*)d_in[4];
    const float* gcn_b = (const float*)d_in[5];
    const float* fc_W  = (const float*)d_in[6];
    const float* fc_b  = (const float*)d_in[7];
    const int*   eidx  = (const int*)d_in[8];
    int E = in_sizes[8] / 2;
    const int* esrc = eidx;
    const int* edst = eidx + E;

    float* out = (float*)d_out;

    // workspace layout (64B aligned blocks)
    char* w = (char*)d_ws;
    int*          counts = (int*)         (w + 0);          // 24,000
    int*          bar    = (int*)         (w + 24064);      // 4 (pad to 24,128)
    float*        dinv   = (float*)       (w + 24128);      // 24,000 (pad 48,128)
    unsigned int* bucket = (unsigned int*)(w + 48128);      // 3,072,000
    unsigned short* feat = (unsigned short*)(w + 3120128);  // 6,144,000
    unsigned short* H    = (unsigned short*)(w + 9264128);  // 6,144,000
    unsigned short* Wt   = (unsigned short*)(w + 15408128); // 2,097,152
    int*          pir    = (int*)         (w + 17505280);   // 1,600,000

    // zero counts + bar
    hipMemsetAsync(w, 0, 24128, stream);

    fused<<<GRID, 256, 0, stream>>>(xa, xv, xt, ew, gcn_W, gcn_b, fc_W, fc_b,
                                    esrc, edst, E, counts, bar, pir, bucket,
                                    dinv, feat, H, Wt, out);
}

// Round 15
// 214.829 us; speedup vs baseline: 5.8337x; 5.8337x over previous
//
#include <hip/hip_runtime.h>
#include <hip/hip_bf16.h>

// Problem constants (from reference)
#define LL 2000
#define MM 3
#define FF 512
#define NN (MM * LL)          // 6000 nodes
#define CAP 128               // bucket capacity; deg ~ N(66.7, 8.2) -> P(any>128) ~ 1e-9

typedef __attribute__((ext_vector_type(8))) short bf16x8;
typedef __attribute__((ext_vector_type(4))) float f32x4;

__device__ __forceinline__ unsigned short f2bf(float x) {
    __hip_bfloat16 b = __float2bfloat16(x);
    return *(unsigned short*)&b;
}

// async global->LDS, 16B per lane. lds dest is wave-uniform base + lane*16.
__device__ __forceinline__ void gload16(const void* gsrc, void* ldst) {
    __builtin_amdgcn_global_load_lds((const __attribute__((address_space(1))) unsigned int*)gsrc,
                                     (__attribute__((address_space(3))) unsigned int*)ldst,
                                     16, 0, 0);
}

// ---------------------------------------------------------------------------
// Fused prep: block-range dispatch.
//  [0, 3000):     concat [x_a;x_v;x_t] -> feat bf16, out fp32 init
//  [3000, 3256):  weight transpose+cvt, slots: 0=gW0^T 1=fW0^T 2=gW1^T 3=fW1^T
//  [3256, ...):   edge histogram: pir[e] = rank of edge e within its row
// ---------------------------------------------------------------------------
__global__ __launch_bounds__(256) void prep(const float* __restrict__ xa,
                                            const float* __restrict__ xv,
                                            const float* __restrict__ xt,
                                            unsigned short* __restrict__ feat,
                                            float* __restrict__ out_sum,
                                            const float* __restrict__ gcnW,
                                            const float* __restrict__ fcW,
                                            unsigned short* __restrict__ Wt,
                                            const int* __restrict__ esrc,
                                            int* __restrict__ counts,
                                            int* __restrict__ pir, int E) {
    __shared__ unsigned short tile[64][65];
    int b = blockIdx.x;
    int tid = threadIdx.x;
    if (b < 3000) {
        // ----- concat -----
        int idx4 = b * 256 + tid;
        const int per4 = (LL * FF) / 4;
        const float4* src;
        int off;
        if (idx4 < per4)            { src = (const float4*)xa; off = idx4; }
        else if (idx4 < 2 * per4)   { src = (const float4*)xv; off = idx4 - per4; }
        else                        { src = (const float4*)xt; off = idx4 - 2 * per4; }
        float4 v = src[off];
        ((float4*)out_sum)[idx4] = v;
        ushort4 pk;
        pk.x = f2bf(v.x); pk.y = f2bf(v.y); pk.z = f2bf(v.z); pk.w = f2bf(v.w);
        ((ushort4*)feat)[idx4] = pk;
    } else if (b < 3256) {
        // ----- wtrans -----
        int idx = b - 3000;
        int mz = idx >> 6;          // 0,1 gcn ; 2,3 fc
        int rem = idx & 63;
        int k0 = (rem >> 3) * 64;
        int n0 = (rem & 7) * 64;
        int layer = (mz < 2) ? mz : mz - 2;
        const float* src = (mz < 2) ? (gcnW + (size_t)layer * FF * FF)
                                    : (fcW + (size_t)layer * FF * FF);
        int slot = (mz < 2) ? (mz * 2) : ((mz - 2) * 2 + 1);
        unsigned short* dst = Wt + (size_t)slot * FF * FF;
        for (int i = tid; i < 64 * 64; i += 256) {
            int r = i >> 6, c = i & 63;
            tile[r][c] = f2bf(src[(size_t)(k0 + r) * FF + n0 + c]);
        }
        __syncthreads();
        for (int i = tid; i < 64 * 64; i += 256) {
            int r = i >> 6, c = i & 63;
            dst[(size_t)(n0 + r) * FF + k0 + c] = tile[c][r];
        }
    } else {
        // ----- edge histogram -----
        int e = (b - 3256) * 256 + tid;
        if (e < E) pir[e] = atomicAdd(&counts[esrc[e]], 1);
    }
}

// ---------------------------------------------------------------------------
// Merged dispatch: scatter blocks [0, sblk) + gemm0 blocks [sblk, ...).
// Scatter first: long-latency random stores start earliest, hide under MFMA.
// scatter (atomic-free, 4B packed): bucket[r*CAP + pir[e]] = bf16(w)<<16 | col
// gemm0: H = feat @ gW0 (64x64 tile, store bf16).
// ---------------------------------------------------------------------------
__global__ __launch_bounds__(256) void gemm0_scatter(const unsigned short* __restrict__ A,
                                                     const unsigned short* __restrict__ Bt,
                                                     unsigned short* __restrict__ Hout,
                                                     int M, int gxm, int sblk,
                                                     const int* __restrict__ esrc,
                                                     const int* __restrict__ edst,
                                                     const float* __restrict__ ew,
                                                     const int* __restrict__ pir,
                                                     unsigned int* __restrict__ bucket, int E) {
    __shared__ short As[64 * 64];
    __shared__ short Bs[64 * 64];
    int b = blockIdx.x;
    int tid = threadIdx.x;
    if (b < sblk) {
        // ----- scatter -----
        int e = b * 256 + tid;
        if (e < E) {
            int r = esrc[e];
            int slot = pir[e];
            if (slot < CAP)
                bucket[(size_t)r * CAP + slot] =
                    ((unsigned int)f2bf(ew[e]) << 16) | (unsigned int)edst[e];
        }
        return;
    }
    // ----- gemm0 -----
    int bg = b - sblk;
    int wave = tid >> 6;
    int lane = tid & 63;
    int lane16 = lane & 15;
    int quad = lane >> 4;
    int m0 = (bg % gxm) * 64;
    int n0 = (bg / gxm) * 64;
    int wm = (wave >> 1) * 32;
    int wn = (wave & 1) * 32;

    f32x4 acc[2][2] = {};

    for (int k0 = 0; k0 < FF; k0 += 64) {
#pragma unroll
        for (int s = 0; s < 2; s++) {
            int c = wave * 128 + s * 64 + lane;
            int row = c >> 3;
            int kc = (c & 7) ^ (row & 7);
            int ar = m0 + row; if (ar >= M) ar = M - 1;
            gload16((const short*)A + (size_t)ar * FF + k0 + kc * 8,
                    &As[(wave * 128 + s * 64) * 8]);
            gload16((const short*)Bt + (size_t)(n0 + row) * FF + k0 + kc * 8,
                    &Bs[(wave * 128 + s * 64) * 8]);
        }
        __syncthreads();
#pragma unroll
        for (int kk = 0; kk < 2; kk++) {
            bf16x8 a[2], bb[2];
#pragma unroll
            for (int mt = 0; mt < 2; mt++) {
                int row = wm + mt * 16 + lane16;
                int kc = (kk * 4 + quad) ^ (row & 7);
                a[mt] = *(const bf16x8*)&As[row * 64 + kc * 8];
            }
#pragma unroll
            for (int nt = 0; nt < 2; nt++) {
                int row = wn + nt * 16 + lane16;
                int kc = (kk * 4 + quad) ^ (row & 7);
                bb[nt] = *(const bf16x8*)&Bs[row * 64 + kc * 8];
            }
#pragma unroll
            for (int mt = 0; mt < 2; mt++)
#pragma unroll
                for (int nt = 0; nt < 2; nt++)
                    acc[mt][nt] = __builtin_amdgcn_mfma_f32_16x16x32_bf16(a[mt], bb[nt], acc[mt][nt], 0, 0, 0);
        }
        __syncthreads();
    }

#pragma unroll
    for (int mt = 0; mt < 2; mt++) {
#pragma unroll
        for (int nt = 0; nt < 2; nt++) {
            int n = n0 + wn + nt * 16 + lane16;
#pragma unroll
            for (int rr = 0; rr < 4; rr++) {
                int m = m0 + wm + mt * 16 + quad * 4 + rr;
                if (m < M) Hout[(size_t)m * FF + n] = f2bf(acc[mt][nt][rr]);
            }
        }
    }
}

// ---------------------------------------------------------------------------
// Row sums over packed buckets -> dinv. One wave per row, 4 rows/block.
// ---------------------------------------------------------------------------
__global__ __launch_bounds__(256) void rowsum_dinv(const unsigned int* __restrict__ bucket,
                                                   const int* __restrict__ counts,
                                                   float* __restrict__ dinv) {
    int wave = threadIdx.x >> 6, lane = threadIdx.x & 63;
    int r = blockIdx.x * 4 + wave;
    int s = r * CAP;
    int e = s + min(counts[r], CAP);
    float sum = 0.0f;
    for (int i = s + lane; i < e; i += 64)
        sum += __uint_as_float(bucket[i] & 0xFFFF0000u);
#pragma unroll
    for (int off = 32; off > 0; off >>= 1) sum += __shfl_xor(sum, off);
    if (lane == 0) dinv[r] = (sum > 0.0f) ? rsqrtf(sum) : 0.0f;
}

// ---------------------------------------------------------------------------
// SpMM gather over packed buckets:
//   feat[r,:] = relu( dinv[r] * sum_e (w_e*dinv[c_e]) * H[c_e,:] + bias )
// One WAVE per row; lane covers 8 features (16B dwordx4 -> full 1KB H row per
// wave-load). UNROLL-8: two uint4 packed-edge prefetches keep 8 H-row loads
// in flight per wave (latency-bound gather -> more MLP).
// ---------------------------------------------------------------------------
__device__ __forceinline__ void accum8(float* acc, uint4 h, float v) {
    unsigned int d[4] = {h.x, h.y, h.z, h.w};
#pragma unroll
    for (int k = 0; k < 4; k++) {
        float lo = __uint_as_float(d[k] << 16);
        float hi = __uint_as_float(d[k] & 0xFFFF0000u);
        acc[2 * k]     = fmaf(v, lo, acc[2 * k]);
        acc[2 * k + 1] = fmaf(v, hi, acc[2 * k + 1]);
    }
}

__global__ __launch_bounds__(256) void spmm_bias_relu(const unsigned short* __restrict__ H,
                                                      const int* __restrict__ counts,
                                                      const unsigned int* __restrict__ bucket,
                                                      const float* __restrict__ dinv,
                                                      const float* __restrict__ bias,
                                                      unsigned short* __restrict__ featOut) {
    int wave = threadIdx.x >> 6, lane = threadIdx.x & 63;
    int r = blockIdx.x * 4 + wave;
    int s = r * CAP;
    int e = s + min(counts[r], CAP);
    int f0 = lane * 8;
    const unsigned short* Hf = H + f0;
    float acc[8] = {0, 0, 0, 0, 0, 0, 0, 0};

    int i = s;
    uint4 pk0, pk1;
    bool have8 = (i + 8 <= e);
    if (have8) { pk0 = *(const uint4*)&bucket[i]; pk1 = *(const uint4*)&bucket[i + 4]; }
    while (have8) {
        unsigned int q0 = pk0.x, q1 = pk0.y, q2 = pk0.z, q3 = pk0.w;
        unsigned int q4 = pk1.x, q5 = pk1.y, q6 = pk1.z, q7 = pk1.w;
        uint4 a0 = *(const uint4*)(Hf + (size_t)(q0 & 0xFFFF) * FF);
        uint4 a1 = *(const uint4*)(Hf + (size_t)(q1 & 0xFFFF) * FF);
        uint4 a2 = *(const uint4*)(Hf + (size_t)(q2 & 0xFFFF) * FF);
        uint4 a3 = *(const uint4*)(Hf + (size_t)(q3 & 0xFFFF) * FF);
        uint4 a4 = *(const uint4*)(Hf + (size_t)(q4 & 0xFFFF) * FF);
        uint4 a5 = *(const uint4*)(Hf + (size_t)(q5 & 0xFFFF) * FF);
        uint4 a6 = *(const uint4*)(Hf + (size_t)(q6 & 0xFFFF) * FF);
        uint4 a7 = *(const uint4*)(Hf + (size_t)(q7 & 0xFFFF) * FF);
        float v0 = __uint_as_float(q0 & 0xFFFF0000u) * dinv[q0 & 0xFFFF];
        float v1 = __uint_as_float(q1 & 0xFFFF0000u) * dinv[q1 & 0xFFFF];
        float v2 = __uint_as_float(q2 & 0xFFFF0000u) * dinv[q2 & 0xFFFF];
        float v3 = __uint_as_float(q3 & 0xFFFF0000u) * dinv[q3 & 0xFFFF];
        float v4 = __uint_as_float(q4 & 0xFFFF0000u) * dinv[q4 & 0xFFFF];
        float v5 = __uint_as_float(q5 & 0xFFFF0000u) * dinv[q5 & 0xFFFF];
        float v6 = __uint_as_float(q6 & 0xFFFF0000u) * dinv[q6 & 0xFFFF];
        float v7 = __uint_as_float(q7 & 0xFFFF0000u) * dinv[q7 & 0xFFFF];
        i += 8;
        have8 = (i + 8 <= e);
        if (have8) { pk0 = *(const uint4*)&bucket[i]; pk1 = *(const uint4*)&bucket[i + 4]; }
        accum8(acc, a0, v0);
        accum8(acc, a1, v1);
        accum8(acc, a2, v2);
        accum8(acc, a3, v3);
        accum8(acc, a4, v4);
        accum8(acc, a5, v5);
        accum8(acc, a6, v6);
        accum8(acc, a7, v7);
    }
    for (; i < e; i++) {
        unsigned int q = bucket[i];
        uint4 a = *(const uint4*)(Hf + (size_t)(q & 0xFFFF) * FF);
        accum8(acc, a, __uint_as_float(q & 0xFFFF0000u) * dinv[q & 0xFFFF]);
    }

    float dr = dinv[r];
    float4 b0 = *(const float4*)(bias + f0);
    float4 b1 = *(const float4*)(bias + f0 + 4);
    float bb[8] = {b0.x, b0.y, b0.z, b0.w, b1.x, b1.y, b1.z, b1.w};
    unsigned int o[4];
#pragma unroll
    for (int k = 0; k < 4; k++) {
        float v0 = fmaxf(fmaf(acc[2 * k], dr, bb[2 * k]), 0.0f);
        float v1 = fmaxf(fmaf(acc[2 * k + 1], dr, bb[2 * k + 1]), 0.0f);
        o[k] = (unsigned int)f2bf(v0) | ((unsigned int)f2bf(v1) << 16);
    }
    uint4 ov; ov.x = o[0]; ov.y = o[1]; ov.z = o[2]; ov.w = o[3];
    *(uint4*)(featOut + (size_t)r * FF + f0) = ov;
}

// ---------------------------------------------------------------------------
// MFMA GEMM over stacked transposed weights Bt[n][k]. 64x64 tile, BK=64,
// 256 threads = 4 waves (2x2 of 32x32), XOR-swizzled LDS.
// MODE 1: all cols -> out += leaky_relu(v + fbias[n]), grid.y = 8
// MODE 2: n0<512 -> out += leaky_relu(v + fbias[n]); n0>=512 -> H store at
//         n-512, grid.y = 16 (Bt = [fW_i^T ; gW_{i+1}^T], same input feat)
// ---------------------------------------------------------------------------
template <int MODE>
__global__ __launch_bounds__(256) void gemm_bf16(const unsigned short* __restrict__ A,
                                                 const unsigned short* __restrict__ Bt,
                                                 const float* __restrict__ fbias,
                                                 unsigned short* __restrict__ Hout,
                                                 float* __restrict__ out,
                                                 int M) {
    __shared__ short As[64 * 64];
    __shared__ short Bs[64 * 64];
    int tid = threadIdx.x;
    int wave = tid >> 6;
    int lane = tid & 63;
    int lane16 = lane & 15;
    int quad = lane >> 4;
    int m0 = blockIdx.x * 64;
    int n0 = blockIdx.y * 64;
    int wm = (wave >> 1) * 32;
    int wn = (wave & 1) * 32;

    f32x4 acc[2][2] = {};

    for (int k0 = 0; k0 < FF; k0 += 64) {
#pragma unroll
        for (int s = 0; s < 2; s++) {
            int c = wave * 128 + s * 64 + lane;
            int row = c >> 3;
            int kc = (c & 7) ^ (row & 7);
            int ar = m0 + row; if (ar >= M) ar = M - 1;
            gload16((const short*)A + (size_t)ar * FF + k0 + kc * 8,
                    &As[(wave * 128 + s * 64) * 8]);
            gload16((const short*)Bt + (size_t)(n0 + row) * FF + k0 + kc * 8,
                    &Bs[(wave * 128 + s * 64) * 8]);
        }
        __syncthreads();
#pragma unroll
        for (int kk = 0; kk < 2; kk++) {
            bf16x8 a[2], bb[2];
#pragma unroll
            for (int mt = 0; mt < 2; mt++) {
                int row = wm + mt * 16 + lane16;
                int kc = (kk * 4 + quad) ^ (row & 7);
                a[mt] = *(const bf16x8*)&As[row * 64 + kc * 8];
            }
#pragma unroll
            for (int nt = 0; nt < 2; nt++) {
                int row = wn + nt * 16 + lane16;
                int kc = (kk * 4 + quad) ^ (row & 7);
                bb[nt] = *(const bf16x8*)&Bs[row * 64 + kc * 8];
            }
#pragma unroll
            for (int mt = 0; mt < 2; mt++)
#pragma unroll
                for (int nt = 0; nt < 2; nt++)
                    acc[mt][nt] = __builtin_amdgcn_mfma_f32_16x16x32_bf16(a[mt], bb[nt], acc[mt][nt], 0, 0, 0);
        }
        __syncthreads();
    }

    bool isFc = (MODE == 1) || (MODE == 2 && n0 < FF);
#pragma unroll
    for (int mt = 0; mt < 2; mt++) {
#pragma unroll
        for (int nt = 0; nt < 2; nt++) {
            int n = n0 + wn + nt * 16 + lane16;
            float bv = isFc ? fbias[n] : 0.0f;
#pragma unroll
            for (int rr = 0; rr < 4; rr++) {
                int m = m0 + wm + mt * 16 + quad * 4 + rr;
                if (m < M) {
                    float v = acc[mt][nt][rr];
                    if (isFc) {
                        v += bv;
                        v = (v > 0.0f) ? v : 0.01f * v;
                        out[(size_t)m * FF + n] += v;
                    } else {
                        Hout[(size_t)m * FF + (n - FF)] = f2bf(v);
                    }
                }
            }
        }
    }
}

// ---------------------------------------------------------------------------
extern "C" void kernel_launch(void* const* d_in, const int* in_sizes, int n_in,
                              void* d_out, int out_size, void* d_ws, size_t ws_size,
                              hipStream_t stream) {
    const float* xa      = (const float*)d_in[0];
    const float* xv      = (const float*)d_in[1];
    const float* xt      = (const float*)d_in[2];
    const float* ew      = (const float*)d_in[3];
    const float* gcn_W   = (const float*)d_in[4];
    const float* gcn_b   = (const float*)d_in[5];
    const float* fc_W    = (const float*)d_in[6];
    const float* fc_b    = (const float*)d_in[7];
    const int*   eidx    = (const int*)d_in[8];
    const int E = in_sizes[8] / 2;
    const int* esrc = eidx;
    const int* edst = eidx + E;

    float* out = (float*)d_out;

    // workspace layout (64B aligned blocks)
    char* w = (char*)d_ws;
    int*          counts = (int*)         (w + 0);          // 24,000 (pad 24,064)
    float*        dinv   = (float*)       (w + 24064);      // 24,000 (pad 48,128)
    unsigned int* bucket = (unsigned int*)(w + 48128);      // 6000*128*4 = 3,072,000
    unsigned short* feat = (unsigned short*)(w + 3120128);  // 6,144,000
    unsigned short* H    = (unsigned short*)(w + 9264128);  // 6,144,000
    unsigned short* Wt   = (unsigned short*)(w + 15408128); // 2,097,152
    int*          pir    = (int*)         (w + 17505280);   // E*4 = 1,600,000

    hipMemsetAsync(counts, 0, 24000, stream);

    const int eblocks = (E + 255) / 256;
    prep<<<3256 + eblocks, 256, 0, stream>>>(xa, xv, xt, feat, out,
                                             gcn_W, fc_W, Wt, esrc, counts, pir, E);

    const int gxm = (NN + 63) / 64;   // 94
    const int ngemm0 = gxm * 8;       // 752
    // Wt slots: 0=gW0^T, 1=fW0^T, 2=gW1^T, 3=fW1^T (slots 1,2 contiguous)
    // merged: scatter (first, starts early) || H0 = feat0 @ gW0
    gemm0_scatter<<<eblocks + ngemm0, 256, 0, stream>>>(feat, Wt, H, NN, gxm, eblocks,
                                                        esrc, edst, ew, pir, bucket, E);
    rowsum_dinv<<<NN / 4, 256, 0, stream>>>(bucket, counts, dinv);

    // feat1 = relu(gcn@H0 + gb0)
    spmm_bias_relu<<<NN / 4, 256, 0, stream>>>(H, counts, bucket, dinv, gcn_b, feat);
    // out += leaky(feat1@fW0 + fb0)  AND  H1 = feat1 @ gW1   (fused)
    gemm_bf16<2><<<dim3(gxm, 16), 256, 0, stream>>>(feat, Wt + (size_t)FF * FF, fc_b, H, out, NN);
    // feat2 = relu(gcn@H1 + gb1)
    spmm_bias_relu<<<NN / 4, 256, 0, stream>>>(H, counts, bucket, dinv, gcn_b + FF, feat);
    // out += leaky(feat2@fW1 + fb1)
    gemm_bf16<1><<<dim3(gxm, 8), 256, 0, stream>>>(feat, Wt + (size_t)3 * FF * FF, fc_b + FF, nullptr, out, NN);
}

// Round 16
// 207.644 us; speedup vs baseline: 6.0355x; 1.0346x over previous
//
#include <hip/hip_runtime.h>
#include <hip/hip_bf16.h>

// Problem constants (from reference)
#define LL 2000
#define MM 3
#define FF 512
#define NN (MM * LL)          // 6000 nodes
#define CAP 128               // bucket capacity; deg ~ N(66.7, 8.2) -> P(any>128) ~ 1e-9

typedef __attribute__((ext_vector_type(8))) short bf16x8;
typedef __attribute__((ext_vector_type(4))) float f32x4;

__device__ __forceinline__ unsigned short f2bf(float x) {
    __hip_bfloat16 b = __float2bfloat16(x);
    return *(unsigned short*)&b;
}

// async global->LDS, 16B per lane. lds dest is wave-uniform base + lane*16.
__device__ __forceinline__ void gload16(const void* gsrc, void* ldst) {
    __builtin_amdgcn_global_load_lds((const __attribute__((address_space(1))) unsigned int*)gsrc,
                                     (__attribute__((address_space(3))) unsigned int*)ldst,
                                     16, 0, 0);
}

// ---------------------------------------------------------------------------
// Fused prep: block-range dispatch.
//  [0, 3000):     concat [x_a;x_v;x_t] -> feat bf16 ONLY (out init now fused
//                 into the first fc GEMM epilogue — saves 12 MB of writes)
//  [3000, 3256):  weight transpose+cvt, slots: 0=gW0^T 1=fW0^T 2=gW1^T 3=fW1^T
//  [3256, ...):   edge histogram: pir[e] = rank of edge e within its row
// ---------------------------------------------------------------------------
__global__ __launch_bounds__(256) void prep(const float* __restrict__ xa,
                                            const float* __restrict__ xv,
                                            const float* __restrict__ xt,
                                            unsigned short* __restrict__ feat,
                                            const float* __restrict__ gcnW,
                                            const float* __restrict__ fcW,
                                            unsigned short* __restrict__ Wt,
                                            const int* __restrict__ esrc,
                                            int* __restrict__ counts,
                                            int* __restrict__ pir, int E) {
    __shared__ unsigned short tile[64][65];
    int b = blockIdx.x;
    int tid = threadIdx.x;
    if (b < 3000) {
        // ----- concat -----
        int idx4 = b * 256 + tid;
        const int per4 = (LL * FF) / 4;
        const float4* src;
        int off;
        if (idx4 < per4)            { src = (const float4*)xa; off = idx4; }
        else if (idx4 < 2 * per4)   { src = (const float4*)xv; off = idx4 - per4; }
        else                        { src = (const float4*)xt; off = idx4 - 2 * per4; }
        float4 v = src[off];
        ushort4 pk;
        pk.x = f2bf(v.x); pk.y = f2bf(v.y); pk.z = f2bf(v.z); pk.w = f2bf(v.w);
        ((ushort4*)feat)[idx4] = pk;
    } else if (b < 3256) {
        // ----- wtrans -----
        int idx = b - 3000;
        int mz = idx >> 6;          // 0,1 gcn ; 2,3 fc
        int rem = idx & 63;
        int k0 = (rem >> 3) * 64;
        int n0 = (rem & 7) * 64;
        int layer = (mz < 2) ? mz : mz - 2;
        const float* src = (mz < 2) ? (gcnW + (size_t)layer * FF * FF)
                                    : (fcW + (size_t)layer * FF * FF);
        int slot = (mz < 2) ? (mz * 2) : ((mz - 2) * 2 + 1);
        unsigned short* dst = Wt + (size_t)slot * FF * FF;
        for (int i = tid; i < 64 * 64; i += 256) {
            int r = i >> 6, c = i & 63;
            tile[r][c] = f2bf(src[(size_t)(k0 + r) * FF + n0 + c]);
        }
        __syncthreads();
        for (int i = tid; i < 64 * 64; i += 256) {
            int r = i >> 6, c = i & 63;
            dst[(size_t)(n0 + r) * FF + k0 + c] = tile[c][r];
        }
    } else {
        // ----- edge histogram -----
        int e = (b - 3256) * 256 + tid;
        if (e < E) pir[e] = atomicAdd(&counts[esrc[e]], 1);
    }
}

// ---------------------------------------------------------------------------
// Merged dispatch: scatter blocks [0, sblk) + gemm0 blocks [sblk, ...).
// Scatter first: long-latency random stores start earliest, hide under MFMA.
// scatter (atomic-free, 4B packed): bucket[r*CAP + pir[e]] = bf16(w)<<16 | col
// gemm0: H = feat @ gW0 (64x64 tile, store bf16).
// ---------------------------------------------------------------------------
__global__ __launch_bounds__(256) void gemm0_scatter(const unsigned short* __restrict__ A,
                                                     const unsigned short* __restrict__ Bt,
                                                     unsigned short* __restrict__ Hout,
                                                     int M, int gxm, int sblk,
                                                     const int* __restrict__ esrc,
                                                     const int* __restrict__ edst,
                                                     const float* __restrict__ ew,
                                                     const int* __restrict__ pir,
                                                     unsigned int* __restrict__ bucket, int E) {
    __shared__ short As[64 * 64];
    __shared__ short Bs[64 * 64];
    int b = blockIdx.x;
    int tid = threadIdx.x;
    if (b < sblk) {
        // ----- scatter -----
        int e = b * 256 + tid;
        if (e < E) {
            int r = esrc[e];
            int slot = pir[e];
            if (slot < CAP)
                bucket[(size_t)r * CAP + slot] =
                    ((unsigned int)f2bf(ew[e]) << 16) | (unsigned int)edst[e];
        }
        return;
    }
    // ----- gemm0 -----
    int bg = b - sblk;
    int wave = tid >> 6;
    int lane = tid & 63;
    int lane16 = lane & 15;
    int quad = lane >> 4;
    int m0 = (bg % gxm) * 64;
    int n0 = (bg / gxm) * 64;
    int wm = (wave >> 1) * 32;
    int wn = (wave & 1) * 32;

    f32x4 acc[2][2] = {};

    for (int k0 = 0; k0 < FF; k0 += 64) {
#pragma unroll
        for (int s = 0; s < 2; s++) {
            int c = wave * 128 + s * 64 + lane;
            int row = c >> 3;
            int kc = (c & 7) ^ (row & 7);
            int ar = m0 + row; if (ar >= M) ar = M - 1;
            gload16((const short*)A + (size_t)ar * FF + k0 + kc * 8,
                    &As[(wave * 128 + s * 64) * 8]);
            gload16((const short*)Bt + (size_t)(n0 + row) * FF + k0 + kc * 8,
                    &Bs[(wave * 128 + s * 64) * 8]);
        }
        __syncthreads();
#pragma unroll
        for (int kk = 0; kk < 2; kk++) {
            bf16x8 a[2], bb[2];
#pragma unroll
            for (int mt = 0; mt < 2; mt++) {
                int row = wm + mt * 16 + lane16;
                int kc = (kk * 4 + quad) ^ (row & 7);
                a[mt] = *(const bf16x8*)&As[row * 64 + kc * 8];
            }
#pragma unroll
            for (int nt = 0; nt < 2; nt++) {
                int row = wn + nt * 16 + lane16;
                int kc = (kk * 4 + quad) ^ (row & 7);
                bb[nt] = *(const bf16x8*)&Bs[row * 64 + kc * 8];
            }
#pragma unroll
            for (int mt = 0; mt < 2; mt++)
#pragma unroll
                for (int nt = 0; nt < 2; nt++)
                    acc[mt][nt] = __builtin_amdgcn_mfma_f32_16x16x32_bf16(a[mt], bb[nt], acc[mt][nt], 0, 0, 0);
        }
        __syncthreads();
    }

#pragma unroll
    for (int mt = 0; mt < 2; mt++) {
#pragma unroll
        for (int nt = 0; nt < 2; nt++) {
            int n = n0 + wn + nt * 16 + lane16;
#pragma unroll
            for (int rr = 0; rr < 4; rr++) {
                int m = m0 + wm + mt * 16 + quad * 4 + rr;
                if (m < M) Hout[(size_t)m * FF + n] = f2bf(acc[mt][nt][rr]);
            }
        }
    }
}

// ---------------------------------------------------------------------------
// Row sums over packed buckets -> dinv. One wave per row, 4 rows/block.
// ---------------------------------------------------------------------------
__global__ __launch_bounds__(256) void rowsum_dinv(const unsigned int* __restrict__ bucket,
                                                   const int* __restrict__ counts,
                                                   float* __restrict__ dinv) {
    int wave = threadIdx.x >> 6, lane = threadIdx.x & 63;
    int r = blockIdx.x * 4 + wave;
    int s = r * CAP;
    int e = s + min(counts[r], CAP);
    float sum = 0.0f;
    for (int i = s + lane; i < e; i += 64)
        sum += __uint_as_float(bucket[i] & 0xFFFF0000u);
#pragma unroll
    for (int off = 32; off > 0; off >>= 1) sum += __shfl_xor(sum, off);
    if (lane == 0) dinv[r] = (sum > 0.0f) ? rsqrtf(sum) : 0.0f;
}

// ---------------------------------------------------------------------------
// SpMM gather over packed buckets:
//   feat[r,:] = relu( dinv[r] * sum_e (w_e*dinv[c_e]) * H[c_e,:] + bias )
// One WAVE per row; lane covers 8 features (16B dwordx4 -> full 1KB H row per
// wave-load). 4 edges prefetched per single uint4 load (unroll-4 proven best).
// ---------------------------------------------------------------------------
__device__ __forceinline__ void accum8(float* acc, uint4 h, float v) {
    unsigned int d[4] = {h.x, h.y, h.z, h.w};
#pragma unroll
    for (int k = 0; k < 4; k++) {
        float lo = __uint_as_float(d[k] << 16);
        float hi = __uint_as_float(d[k] & 0xFFFF0000u);
        acc[2 * k]     = fmaf(v, lo, acc[2 * k]);
        acc[2 * k + 1] = fmaf(v, hi, acc[2 * k + 1]);
    }
}

__global__ __launch_bounds__(256) void spmm_bias_relu(const unsigned short* __restrict__ H,
                                                      const int* __restrict__ counts,
                                                      const unsigned int* __restrict__ bucket,
                                                      const float* __restrict__ dinv,
                                                      const float* __restrict__ bias,
                                                      unsigned short* __restrict__ featOut) {
    int wave = threadIdx.x >> 6, lane = threadIdx.x & 63;
    int r = blockIdx.x * 4 + wave;
    int s = r * CAP;
    int e = s + min(counts[r], CAP);
    int f0 = lane * 8;
    const unsigned short* Hf = H + f0;
    float acc[8] = {0, 0, 0, 0, 0, 0, 0, 0};

    int i = s;
    uint4 pk;
    bool have = (i + 4 <= e);
    if (have) pk = *(const uint4*)&bucket[i];
    while (have) {
        unsigned int q0 = pk.x, q1 = pk.y, q2 = pk.z, q3 = pk.w;
        uint4 a0 = *(const uint4*)(Hf + (size_t)(q0 & 0xFFFF) * FF);
        uint4 a1 = *(const uint4*)(Hf + (size_t)(q1 & 0xFFFF) * FF);
        uint4 a2 = *(const uint4*)(Hf + (size_t)(q2 & 0xFFFF) * FF);
        uint4 a3 = *(const uint4*)(Hf + (size_t)(q3 & 0xFFFF) * FF);
        float v0 = __uint_as_float(q0 & 0xFFFF0000u) * dinv[q0 & 0xFFFF];
        float v1 = __uint_as_float(q1 & 0xFFFF0000u) * dinv[q1 & 0xFFFF];
        float v2 = __uint_as_float(q2 & 0xFFFF0000u) * dinv[q2 & 0xFFFF];
        float v3 = __uint_as_float(q3 & 0xFFFF0000u) * dinv[q3 & 0xFFFF];
        i += 4;
        have = (i + 4 <= e);
        if (have) pk = *(const uint4*)&bucket[i];
        accum8(acc, a0, v0);
        accum8(acc, a1, v1);
        accum8(acc, a2, v2);
        accum8(acc, a3, v3);
    }
    for (; i < e; i++) {
        unsigned int q = bucket[i];
        uint4 a = *(const uint4*)(Hf + (size_t)(q & 0xFFFF) * FF);
        accum8(acc, a, __uint_as_float(q & 0xFFFF0000u) * dinv[q & 0xFFFF]);
    }

    float dr = dinv[r];
    float4 b0 = *(const float4*)(bias + f0);
    float4 b1 = *(const float4*)(bias + f0 + 4);
    float bb[8] = {b0.x, b0.y, b0.z, b0.w, b1.x, b1.y, b1.z, b1.w};
    unsigned int o[4];
#pragma unroll
    for (int k = 0; k < 4; k++) {
        float v0 = fmaxf(fmaf(acc[2 * k], dr, bb[2 * k]), 0.0f);
        float v1 = fmaxf(fmaf(acc[2 * k + 1], dr, bb[2 * k + 1]), 0.0f);
        o[k] = (unsigned int)f2bf(v0) | ((unsigned int)f2bf(v1) << 16);
    }
    uint4 ov; ov.x = o[0]; ov.y = o[1]; ov.z = o[2]; ov.w = o[3];
    *(uint4*)(featOut + (size_t)r * FF + f0) = ov;
}

// ---------------------------------------------------------------------------
// MFMA GEMM over stacked transposed weights Bt[n][k]. 64x64 tile, BK=64,
// 256 threads = 4 waves (2x2 of 32x32), XOR-swizzled LDS.
// MODE 1: all cols -> out += leaky_relu(v + fbias[n]), grid.y = 8
// MODE 2: n0<512 -> out = x_concat + leaky_relu(v + fbias[n])  (INIT, no RMW);
//         n0>=512 -> H store at n-512, grid.y = 16
//         (Bt = [fW_i^T ; gW_{i+1}^T], same input feat)
// ---------------------------------------------------------------------------
template <int MODE>
__global__ __launch_bounds__(256) void gemm_bf16(const unsigned short* __restrict__ A,
                                                 const unsigned short* __restrict__ Bt,
                                                 const float* __restrict__ fbias,
                                                 unsigned short* __restrict__ Hout,
                                                 float* __restrict__ out,
                                                 const float* __restrict__ xa,
                                                 const float* __restrict__ xv,
                                                 const float* __restrict__ xt,
                                                 int M) {
    __shared__ short As[64 * 64];
    __shared__ short Bs[64 * 64];
    int tid = threadIdx.x;
    int wave = tid >> 6;
    int lane = tid & 63;
    int lane16 = lane & 15;
    int quad = lane >> 4;
    int m0 = blockIdx.x * 64;
    int n0 = blockIdx.y * 64;
    int wm = (wave >> 1) * 32;
    int wn = (wave & 1) * 32;

    f32x4 acc[2][2] = {};

    for (int k0 = 0; k0 < FF; k0 += 64) {
#pragma unroll
        for (int s = 0; s < 2; s++) {
            int c = wave * 128 + s * 64 + lane;
            int row = c >> 3;
            int kc = (c & 7) ^ (row & 7);
            int ar = m0 + row; if (ar >= M) ar = M - 1;
            gload16((const short*)A + (size_t)ar * FF + k0 + kc * 8,
                    &As[(wave * 128 + s * 64) * 8]);
            gload16((const short*)Bt + (size_t)(n0 + row) * FF + k0 + kc * 8,
                    &Bs[(wave * 128 + s * 64) * 8]);
        }
        __syncthreads();
#pragma unroll
        for (int kk = 0; kk < 2; kk++) {
            bf16x8 a[2], bb[2];
#pragma unroll
            for (int mt = 0; mt < 2; mt++) {
                int row = wm + mt * 16 + lane16;
                int kc = (kk * 4 + quad) ^ (row & 7);
                a[mt] = *(const bf16x8*)&As[row * 64 + kc * 8];
            }
#pragma unroll
            for (int nt = 0; nt < 2; nt++) {
                int row = wn + nt * 16 + lane16;
                int kc = (kk * 4 + quad) ^ (row & 7);
                bb[nt] = *(const bf16x8*)&Bs[row * 64 + kc * 8];
            }
#pragma unroll
            for (int mt = 0; mt < 2; mt++)
#pragma unroll
                for (int nt = 0; nt < 2; nt++)
                    acc[mt][nt] = __builtin_amdgcn_mfma_f32_16x16x32_bf16(a[mt], bb[nt], acc[mt][nt], 0, 0, 0);
        }
        __syncthreads();
    }

    bool isFc = (MODE == 1) || (MODE == 2 && n0 < FF);
#pragma unroll
    for (int mt = 0; mt < 2; mt++) {
#pragma unroll
        for (int nt = 0; nt < 2; nt++) {
            int n = n0 + wn + nt * 16 + lane16;
            float bv = isFc ? fbias[n] : 0.0f;
#pragma unroll
            for (int rr = 0; rr < 4; rr++) {
                int m = m0 + wm + mt * 16 + quad * 4 + rr;
                if (m < M) {
                    float v = acc[mt][nt][rr];
                    if (isFc) {
                        v += bv;
                        v = (v > 0.0f) ? v : 0.01f * v;
                        if (MODE == 2) {
                            // out init: concat value + fc0 contribution
                            const float* xs;
                            int mm = m;
                            if (m < LL)            { xs = xa; }
                            else if (m < 2 * LL)   { xs = xv; mm = m - LL; }
                            else                   { xs = xt; mm = m - 2 * LL; }
                            out[(size_t)m * FF + n] = xs[(size_t)mm * FF + n] + v;
                        } else {
                            out[(size_t)m * FF + n] += v;
                        }
                    } else {
                        Hout[(size_t)m * FF + (n - FF)] = f2bf(v);
                    }
                }
            }
        }
    }
}

// ---------------------------------------------------------------------------
extern "C" void kernel_launch(void* const* d_in, const int* in_sizes, int n_in,
                              void* d_out, int out_size, void* d_ws, size_t ws_size,
                              hipStream_t stream) {
    const float* xa      = (const float*)d_in[0];
    const float* xv      = (const float*)d_in[1];
    const float* xt      = (const float*)d_in[2];
    const float* ew      = (const float*)d_in[3];
    const float* gcn_W   = (const float*)d_in[4];
    const float* gcn_b   = (const float*)d_in[5];
    const float* fc_W    = (const float*)d_in[6];
    const float* fc_b    = (const float*)d_in[7];
    const int*   eidx    = (const int*)d_in[8];
    const int E = in_sizes[8] / 2;
    const int* esrc = eidx;
    const int* edst = eidx + E;

    float* out = (float*)d_out;

    // workspace layout (64B aligned blocks)
    char* w = (char*)d_ws;
    int*          counts = (int*)         (w + 0);          // 24,000 (pad 24,064)
    float*        dinv   = (float*)       (w + 24064);      // 24,000 (pad 48,128)
    unsigned int* bucket = (unsigned int*)(w + 48128);      // 6000*128*4 = 3,072,000
    unsigned short* feat = (unsigned short*)(w + 3120128);  // 6,144,000
    unsigned short* H    = (unsigned short*)(w + 9264128);  // 6,144,000
    unsigned short* Wt   = (unsigned short*)(w + 15408128); // 2,097,152
    int*          pir    = (int*)         (w + 17505280);   // E*4 = 1,600,000

    hipMemsetAsync(counts, 0, 24000, stream);

    const int eblocks = (E + 255) / 256;
    prep<<<3256 + eblocks, 256, 0, stream>>>(xa, xv, xt, feat,
                                             gcn_W, fc_W, Wt, esrc, counts, pir, E);

    const int gxm = (NN + 63) / 64;   // 94
    const int ngemm0 = gxm * 8;       // 752
    // Wt slots: 0=gW0^T, 1=fW0^T, 2=gW1^T, 3=fW1^T (slots 1,2 contiguous)
    // merged: scatter (first, starts early) || H0 = feat0 @ gW0
    gemm0_scatter<<<eblocks + ngemm0, 256, 0, stream>>>(feat, Wt, H, NN, gxm, eblocks,
                                                        esrc, edst, ew, pir, bucket, E);
    rowsum_dinv<<<NN / 4, 256, 0, stream>>>(bucket, counts, dinv);

    // feat1 = relu(gcn@H0 + gb0)
    spmm_bias_relu<<<NN / 4, 256, 0, stream>>>(H, counts, bucket, dinv, gcn_b, feat);
    // out = concat + leaky(feat1@fW0 + fb0)  AND  H1 = feat1 @ gW1   (fused)
    gemm_bf16<2><<<dim3(gxm, 16), 256, 0, stream>>>(feat, Wt + (size_t)FF * FF, fc_b,
                                                    H, out, xa, xv, xt, NN);
    // feat2 = relu(gcn@H1 + gb1)
    spmm_bias_relu<<<NN / 4, 256, 0, stream>>>(H, counts, bucket, dinv, gcn_b + FF, feat);
    // out += leaky(feat2@fW1 + fb1)
    gemm_bf16<1><<<dim3(gxm, 8), 256, 0, stream>>>(feat, Wt + (size_t)3 * FF * FF, fc_b + FF,
                                                   nullptr, out, nullptr, nullptr, nullptr, NN);
}